// Round 9
// baseline (1594.138 us; speedup 1.0000x reference)
//
#include <hip/hip_runtime.h>
#include <hip/hip_bf16.h>

// Shapes (fixed): N=4000, S=32, D=128, L=2, C=10, K=2, THETA=0.5
// Padded: NP=4096 nodes, SD=4096 (=S*D), KBIG=8192 (=2*NP)

typedef __attribute__((ext_vector_type(8))) short short8;
typedef __attribute__((ext_vector_type(4))) float f32x4;
typedef __attribute__((ext_vector_type(4))) unsigned short us4;

__device__ __forceinline__ unsigned short f2bf(float x) {
  unsigned int u = __builtin_bit_cast(unsigned int, x);
  u += 0x7FFFu + ((u >> 16) & 1u);   // RNE
  return (unsigned short)(u >> 16);
}
__device__ __forceinline__ float bf2f(unsigned short u) {
  unsigned int x = ((unsigned int)u) << 16;
  return __builtin_bit_cast(float, x);
}

__device__ __forceinline__ void gload16(const void* g, void* l) {
  __builtin_amdgcn_global_load_lds((const __attribute__((address_space(1))) void*)g,
                                   (__attribute__((address_space(3))) void*)l, 16, 0, 0);
}

__device__ __forceinline__ void barrier_() {
  __builtin_amdgcn_sched_barrier(0);
  asm volatile("" ::: "memory");
  __builtin_amdgcn_s_barrier();
  asm volatile("" ::: "memory");
  __builtin_amdgcn_sched_barrier(0);
}

// ---------------------------------------------------------------------------
// 256x256 NT GEMM, m201-faithful 4-phase/K-tile schedule:
// reads IN-PHASE (issue -> barrier -> lgkmcnt(0) -> MFMA -> barrier), so
// per-wave lgkm completion staggers the MFMA entry and the LDS-read pipe
// overlaps the MFMA pipe across waves (the m198/m201 mechanism).
// LDS 128KiB: A [2][16384], B [2][16384], buf = V&1. XOR slot-swizzle.
// Read map: P1 a0(V)[8], P2 b1(V)[4], P3 a1(V)[8], P4 b0(V+1)[4 after vmcnt].
// Stage map: P1 A1(V+1); P3 B0,B1(V+2); P4 A0(V+2); one vmcnt(6)/tile at P4
// (FIFO: drains exactly all of tile V+1, leaves V+2's 3 half-tiles in
// flight). Write-after-read per region: A1(V+1) -> other buf; B0/B1(V+2)
// regions fully read by end-P2 (b1) / start-of-V (b0); A0(V+2) region fully
// read by end-P3 (a1). Quadrants: P1 Q00(a0,b0) P2 Q01(a0,b1) P3 Q10(a1,b0)
// P4 Q11(a1,b1).
// EPI: TRANS=0 normal bf16 store (opt relu); TRANS=1 C^T us4-packed.
// ---------------------------------------------------------------------------
template<int TRANS, int RELU>
__global__ __launch_bounds__(512, 2)
void gemm256(const unsigned short* __restrict__ Ap, int lda,
             const unsigned short* __restrict__ Bp, int ldb,
             unsigned short* __restrict__ outp, int ldo, int K)
{
  __shared__ alignas(16) unsigned short lds[65536];   // 128 KiB
  const int t = threadIdx.x;
  const int lane = t & 63;
  const int wave = t >> 6;          // 0..7
  const int wm = wave >> 2;         // 0..1
  const int wn = wave & 3;          // 0..3
  const int lrow = lane & 15;
  const int kgrp = lane >> 4;       // 0..3
  const int slotbase = (kgrp ^ (lrow & 7)) << 3;   // ushort units

  // XCD-chunked bijective swizzle (nwg=256, q=32, r=0)
  const int b = blockIdx.x;
  const int wg = (b & 7) * 32 + (b >> 3);
  const int m0 = (wg >> 4) << 8;
  const int j0 = (wg & 15) << 8;

  // staging: thread t covers one 16B block; prow=t>>3, logical slot
  // = (t&7) ^ (prow&7); the 2nd gload of each STG adds 64 rows.
  const int prow = t >> 3;
  const int lslot = (t & 7) ^ (prow & 7);
  const unsigned short* srcA = Ap + (size_t)(m0 + prow) * lda + lslot * 8;
  const unsigned short* srcB = Bp + (size_t)(j0 + prow) * ldb + lslot * 8;
  const size_t a64 = (size_t)64 * lda, a128 = (size_t)128 * lda;
  const size_t b64 = (size_t)64 * ldb, b128 = (size_t)128 * ldb;
  unsigned short* dA = &lds[t * 8];                 // A region: [2][16384]
  unsigned short* dB = &lds[32768 + t * 8];         // B region: [2][16384]
  const int NT = K >> 6;

#define STG_A(h, kb, kt) { const unsigned short* s_ = srcA + (h)*a128 + (size_t)(kt)*64; \
    gload16(s_, dA + (kb)*16384 + (h)*8192); \
    gload16(s_ + a64, dA + (kb)*16384 + (h)*8192 + 4096); }
#define STG_B(h, kb, kt) { const unsigned short* s_ = srcB + (h)*b128 + (size_t)(kt)*64; \
    gload16(s_, dB + (kb)*16384 + (h)*8192); \
    gload16(s_ + b64, dB + (kb)*16384 + (h)*8192 + 4096); }

  // per-lane ds_read bases (relative to buffer), swizzled
  const int arb = wm * 8192 + lrow * 64 + slotbase;
  const int brb = wn * 4096 + lrow * 64 + slotbase;

#define RD_A(dst, base_off) \
  _Pragma("unroll") for (int mf_ = 0; mf_ < 4; ++mf_) { \
    dst[mf_][0] = *(const short8*)&lds[(base_off) + mf_*1024]; \
    dst[mf_][1] = *(const short8*)&lds[((base_off) ^ 32) + mf_*1024]; }
#define RD_B(dst, base_off) \
  _Pragma("unroll") for (int nf_ = 0; nf_ < 2; ++nf_) { \
    dst[nf_][0] = *(const short8*)&lds[(base_off) + nf_*1024]; \
    dst[nf_][1] = *(const short8*)&lds[((base_off) ^ 32) + nf_*1024]; }

#define MFMA16(AF, BF, MB, NB) \
  _Pragma("unroll") for (int mf_ = 0; mf_ < 4; ++mf_) \
  _Pragma("unroll") for (int nf_ = 0; nf_ < 2; ++nf_) { \
    acc[(MB)+mf_][(NB)+nf_] = __builtin_amdgcn_mfma_f32_16x16x32_bf16(AF[mf_][0], BF[nf_][0], acc[(MB)+mf_][(NB)+nf_], 0,0,0); \
    acc[(MB)+mf_][(NB)+nf_] = __builtin_amdgcn_mfma_f32_16x16x32_bf16(AF[mf_][1], BF[nf_][1], acc[(MB)+mf_][(NB)+nf_], 0,0,0); }

#define LGKM0 { asm volatile("s_waitcnt lgkmcnt(0)" ::: "memory"); \
                __builtin_amdgcn_sched_barrier(0); }

  f32x4 acc[8][4];
#pragma unroll
  for (int i = 0; i < 8; ++i)
#pragma unroll
    for (int j = 0; j < 4; ++j) acc[i][j] = f32x4{0.f, 0.f, 0.f, 0.f};

  short8 a0[4][2], a1[4][2], b0[2][2], b1[2][2];

  // prologue: tile0 fully (8 loads) + tile1's B0,B1,A0 (6 loads);
  // vmcnt(6) guarantees tile0, leaves tile1's 3 half-tiles in flight.
  STG_A(0, 0, 0); STG_A(1, 0, 0); STG_B(0, 0, 0); STG_B(1, 0, 0);
  STG_B(0, 1, 1); STG_B(1, 1, 1); STG_A(0, 1, 1);
  asm volatile("s_waitcnt vmcnt(6)" ::: "memory");
  barrier_();
  RD_B(b0, 32768 + brb);    // b0(0); completion enforced by P1's lgkm0

  for (int V = 0; V < NT; ++V) {
    const int abuf = (V & 1) << 14;
    const int bbuf = 32768 + ((V & 1) << 14);
    const bool st1 = (V + 1 < NT);
    const bool st2 = (V + 2 < NT);

    // ---- P1: read a0(V); stage A1(V+1) [other buf]; Q00 ----
    RD_A(a0, abuf + arb);
    if (st1) STG_A(1, (V + 1) & 1, V + 1);
    barrier_(); LGKM0;
    __builtin_amdgcn_s_setprio(1);
    MFMA16(a0, b0, 0, 0);
    __builtin_amdgcn_s_setprio(0);
    barrier_();

    // ---- P2: read b1(V); Q01 ----
    RD_B(b1, bbuf + brb + 2048);
    barrier_(); LGKM0;
    __builtin_amdgcn_s_setprio(1);
    MFMA16(a0, b1, 0, 2);
    __builtin_amdgcn_s_setprio(0);
    barrier_();

    // ---- P3: read a1(V); stage B0,B1(V+2) [b-regions read-proven @P2] ----
    RD_A(a1, abuf + arb + 4096);
    if (st2) { STG_B(0, V & 1, V + 2); STG_B(1, V & 1, V + 2); }
    barrier_(); LGKM0;
    __builtin_amdgcn_s_setprio(1);
    MFMA16(a1, b0, 4, 0);
    __builtin_amdgcn_s_setprio(0);
    barrier_();

    // ---- P4: stage A0(V+2) [a-region read-proven @P3]; vmcnt;
    //          read b0(V+1) [guaranteed by the vmcnt]; Q11 ----
    if (st2) STG_A(0, V & 1, V + 2);
    if (st2)      { asm volatile("s_waitcnt vmcnt(6)" ::: "memory"); }
    else if (st1) { asm volatile("s_waitcnt vmcnt(0)" ::: "memory"); }
    if (st1) RD_B(b0, 32768 + (((V + 1) & 1) << 14) + brb);
    barrier_(); LGKM0;
    __builtin_amdgcn_s_setprio(1);
    MFMA16(a1, b1, 4, 2);
    __builtin_amdgcn_s_setprio(0);
    barrier_();
  }

  // epilogue: C/D layout col=lane&15, row=(lane>>4)*4+r
#pragma unroll
  for (int mf = 0; mf < 8; ++mf) {
#pragma unroll
    for (int nf = 0; nf < 4; ++nf) {
      const int m = m0 + wm * 128 + mf * 16 + kgrp * 4;
      const int j = j0 + wn * 64 + nf * 16 + lrow;
      if (TRANS) {
        us4 pk;
#pragma unroll
        for (int r = 0; r < 4; ++r) pk[r] = f2bf(acc[mf][nf][r]);
        *(us4*)(outp + (size_t)j * ldo + m) = pk;
      } else {
#pragma unroll
        for (int r = 0; r < 4; ++r) {
          float v = acc[mf][nf][r];
          if (RELU) v = fmaxf(v, 0.f);
          outp[(size_t)(m + r) * ldo + j] = f2bf(v);
        }
      }
    }
  }
#undef STG_A
#undef STG_B
#undef RD_A
#undef RD_B
#undef MFMA16
#undef LGKM0
}

// ---------------------------------------------------------------------------
// Small-K NT GEMM: stage the ENTIRE K (<=256) upfront, ONE barrier, then all
// MFMAs. 128x128 tile, 4 waves (2x2), 4x4 frags.
// EPI 0: transposed bf16 store; EPI 2: f32 + bias; EPI 3: tanh f32 scatter.
// ---------------------------------------------------------------------------
template<int EPI, int KFULL, int MINB>
__global__ __launch_bounds__(256, MINB)
void gemm_smallk(const unsigned short* __restrict__ A1,
                 const unsigned short* __restrict__ A2,
                 int k_switch, int a_zstride, int lda,
                 const unsigned short* __restrict__ B, int ldb,
                 void* __restrict__ outp,
                 long o_j, long o_m, long o_z, long o_jt,
                 const float* __restrict__ bias)
{
  __shared__ alignas(16) unsigned short At[(KFULL / 32) * 4096];
  __shared__ alignas(16) unsigned short Bt[(KFULL / 32) * 4096];
  const int t = threadIdx.x;
  const int lane = t & 63;
  const int wave = t >> 6;
  const int m0 = blockIdx.x << 7;
  const int jt = blockIdx.y;
  const int j0 = jt << 7;
  const int z  = blockIdx.z;
  const int wm = (wave >> 1) << 6;
  const int wn = (wave & 1) << 6;
  const int lrow = lane & 15;
  const int kgrp = lane >> 4;

  const unsigned short* A1z = A1 + (long)z * a_zstride;
  const unsigned short* A2z = A2 + (long)z * a_zstride;

  const int r0 = t >> 2, q0 = t & 3;
  const int c1 = t + 256;
  const int r1 = c1 >> 2, q1 = c1 & 3;

#pragma unroll
  for (int kk = 0; kk < KFULL / 32; ++kk) {
    const int k0 = kk * 32;
    const unsigned short* As; int ka;
    if (k0 < k_switch) { As = A1z; ka = k0; } else { As = A2z; ka = k0 - k_switch; }
    gload16(As + (long)(m0 + r0) * lda + ka + q0 * 8, At + kk * 4096 + t * 8);
    gload16(As + (long)(m0 + r1) * lda + ka + q1 * 8, At + kk * 4096 + c1 * 8);
    gload16(B  + (long)(j0 + r0) * ldb + k0 + q0 * 8, Bt + kk * 4096 + t * 8);
    gload16(B  + (long)(j0 + r1) * ldb + k0 + q1 * 8, Bt + kk * 4096 + c1 * 8);
  }
  __syncthreads();   // drains vmcnt(0)

  f32x4 acc[4][4];
#pragma unroll
  for (int i = 0; i < 4; ++i)
#pragma unroll
    for (int j = 0; j < 4; ++j) acc[i][j] = f32x4{0.f, 0.f, 0.f, 0.f};

#pragma unroll
  for (int kk = 0; kk < KFULL / 32; ++kk) {
    short8 af[4], bv[4];
#pragma unroll
    for (int i = 0; i < 4; ++i)
      af[i] = *(const short8*)(At + kk * 4096 + (wm + i * 16 + lrow) * 32 + kgrp * 8);
#pragma unroll
    for (int i = 0; i < 4; ++i)
      bv[i] = *(const short8*)(Bt + kk * 4096 + (wn + i * 16 + lrow) * 32 + kgrp * 8);
#pragma unroll
    for (int i = 0; i < 4; ++i)
#pragma unroll
      for (int j = 0; j < 4; ++j)
        acc[i][j] = __builtin_amdgcn_mfma_f32_16x16x32_bf16(af[i], bv[j], acc[i][j], 0, 0, 0);
  }

  const int mlb = wm + kgrp * 4;
#pragma unroll
  for (int i = 0; i < 4; ++i) {
#pragma unroll
    for (int j = 0; j < 4; ++j) {
      const int jl = wn + j * 16 + lrow;
      const int ml = mlb + i * 16;
      if (EPI == 0) {
        long base = (long)jl * o_j + (long)(m0 + ml) * o_m + (long)z * o_z + (long)jt * o_jt;
        us4 pk;
#pragma unroll
        for (int r = 0; r < 4; ++r) pk[r] = f2bf(acc[i][j][r]);
        *(us4*)((unsigned short*)outp + base) = pk;
      } else if (EPI == 2) {
        float* of = (float*)outp;
        float badd = bias[j0 + jl];
#pragma unroll
        for (int r = 0; r < 4; ++r) {
          long idx = (long)jl * o_j + (long)(m0 + ml + r) * o_m + (long)z * o_z + (long)jt * o_jt;
          of[idx] = acc[i][j][r] + badd;
        }
      } else {   // EPI == 3: tanh scatter to OUTS
        float* of = (float*)outp;
#pragma unroll
        for (int r = 0; r < 4; ++r) {
          int mm = m0 + ml + r;
          int n = mm & 4095, l = mm >> 12;
          if (n < 4000)
            of[(size_t)l * 512000 + (size_t)n * 128 + (j0 + jl)] = tanhf(acc[i][j][r]);
        }
      }
    }
  }
}

// ---------------------------------------------------------------------------
// Graph-normalization prep
// ---------------------------------------------------------------------------
__global__ __launch_bounds__(256) void rowsum_dis(const float* __restrict__ A,
                                                  float* __restrict__ dis) {
  int m = blockIdx.x;
  if (m >= 4000) { if (threadIdx.x == 0) dis[m] = 0.f; return; }
  const float* r = A + (long)m * 4000;
  float a = 0.f;
  for (int i = threadIdx.x; i < 1000; i += 256) {
    float4 v = ((const float4*)r)[i];
    a += v.x + v.y + v.z + v.w;
  }
  for (int o = 32; o; o >>= 1) a += __shfl_xor(a, o);
  __shared__ float ls[4];
  if ((threadIdx.x & 63) == 0) ls[threadIdx.x >> 6] = a;
  __syncthreads();
  if (threadIdx.x == 0) dis[m] = rsqrtf(1.f + ls[0] + ls[1] + ls[2] + ls[3]);
}

__global__ __launch_bounds__(256) void wrow_kernel(const float* __restrict__ A,
                                                   const float* __restrict__ dis,
                                                   float* __restrict__ iwrow) {
  int m = blockIdx.x;
  if (m >= 4000) { if (threadIdx.x == 0) iwrow[m] = 0.f; return; }
  const float* r = A + (long)m * 4000;
  float a = 0.f;
  for (int n = threadIdx.x; n < 4000; n += 256) a += r[n] * dis[n];
  for (int o = 32; o; o >>= 1) a += __shfl_xor(a, o);
  __shared__ float ls[4];
  if ((threadIdx.x & 63) == 0) ls[threadIdx.x >> 6] = a;
  __syncthreads();
  if (threadIdx.x == 0) iwrow[m] = 1.f / (ls[0] + ls[1] + ls[2] + ls[3] + dis[m]);
}

__global__ __launch_bounds__(256) void wcol_part(const float* __restrict__ A,
                                                 const float* __restrict__ dis,
                                                 float* __restrict__ part) {
  int j = blockIdx.x * 256 + threadIdx.x;   // 0..4095
  int mz = blockIdx.y;                      // 0..31
  float a = 0.f;
  if (j < 4000) {
    int ms = mz * 125;
    for (int m = ms; m < ms + 125; ++m) a += A[(long)m * 4000 + j] * dis[m];
  }
  part[(long)mz * 4096 + j] = a;
}

__global__ __launch_bounds__(256) void wcol_fin(const float* __restrict__ part,
                                                const float* __restrict__ dis,
                                                float* __restrict__ iwcol) {
  int j = blockIdx.x * 256 + threadIdx.x;
  float s = 0.f;
  for (int z = 0; z < 32; ++z) s += part[(long)z * 4096 + j];
  iwcol[j] = (j < 4000) ? 1.f / (s + dis[j]) : 0.f;
}

// P_f into Pcat cols [0,4096); P_vT and P_v (transposed via LDS) separately.
__global__ __launch_bounds__(256) void build_P(const float* __restrict__ A,
                                               const float* __restrict__ dis,
                                               const float* __restrict__ iwrow,
                                               const float* __restrict__ iwcol,
                                               unsigned short* __restrict__ Pcat,
                                               unsigned short* __restrict__ PV,
                                               unsigned short* __restrict__ PVT) {
  __shared__ float tile[64][65];
  int m0 = blockIdx.y * 64, n0 = blockIdx.x * 64;
#pragma unroll
  for (int i = 0; i < 16; ++i) {
    int idx = i * 256 + threadIdx.x;
    int lr = idx >> 6, lc = idx & 63;
    int m = m0 + lr, n = n0 + lc;
    float v = 0.f;
    if (m < 4000 && n < 4000) {
      float a = A[(long)m * 4000 + n];
      if (m == n) a += 1.f;
      v = a * dis[n];
    }
    Pcat[(long)m * 8192 + n] = f2bf(v * iwrow[m]);
    float pv = v * iwcol[m];
    PVT[(long)m * 4096 + n] = f2bf(pv);
    tile[lr][lc] = pv;
  }
  __syncthreads();
#pragma unroll
  for (int i = 0; i < 16; ++i) {
    int idx = i * 256 + threadIdx.x;
    int lr = idx >> 6, lc = idx & 63;
    PV[(long)(n0 + lr) * 4096 + (m0 + lc)] = f2bf(tile[lc][lr]);
  }
}

// Small-weight transposes (one-time)
__global__ __launch_bounds__(256) void prep_weights(const float* __restrict__ lin_out,
                                                    const float* __restrict__ c1,
                                                    const float* __restrict__ c2,
                                                    const float* __restrict__ wpsi,
                                                    unsigned short* __restrict__ CW1T,
                                                    unsigned short* __restrict__ CW2T,
                                                    unsigned short* __restrict__ WPST,
                                                    unsigned short* __restrict__ LWOB) {
  int i = blockIdx.x * 256 + threadIdx.x;
  if (i < 32768) {
    int j = i >> 7, kk = i & 127;
    CW1T[i] = f2bf(c1[(j >> 7) * 16384 + kk * 128 + (j & 127)]);
  } else if (i < 65536) {
    int k = i - 32768; int j = k >> 7, kk = k & 127;
    CW2T[k] = f2bf(c2[(j >> 7) * 16384 + kk * 128 + (j & 127)]);
  } else if (i < 98304) {
    int k = i - 65536; int e = k >> 8, d2 = k & 255;
    WPST[k] = f2bf(0.5f * wpsi[d2 * 128 + e]);
  } else if (i < 131072) {
    int k = i - 98304;
    LWOB[k] = f2bf(lin_out[k]);
  }
}

// WQ[d*256+k2] = sum_e lin_in[d*128+e] * WPST[e*256+k2]  (bf16 out)
// BQ[d] = sum_e bpsi[e] * lin_in[d*128+e]
__global__ __launch_bounds__(256) void wq_prep(const float* __restrict__ lin_in,
                                               const float* __restrict__ bpsi,
                                               const unsigned short* __restrict__ WPST,
                                               unsigned short* __restrict__ WQ,
                                               float* __restrict__ BQ) {
  int b = blockIdx.x, t = threadIdx.x;
  if (b < 128) {
    int idx = b * 256 + t;
    int d = idx >> 8, k2 = idx & 255;
    float acc = 0.f;
    for (int e = 0; e < 128; ++e)
      acc += lin_in[d * 128 + e] * bf2f(WPST[e * 256 + k2]);
    WQ[idx] = f2bf(acc);
  } else if (t < 128) {
    float acc = 0.f;
    for (int e = 0; e < 128; ++e) acc += bpsi[e] * lin_in[t * 128 + e];
    BQ[t] = acc;
  }
}

// embs[l] (S,N,D) -> X_bf (NP, S*D) bf16, pad rows zeroed
__global__ __launch_bounds__(256) void convert_X(const float* __restrict__ embsL,
                                                 unsigned short* __restrict__ X) {
  long i4 = (long)blockIdx.x * 256 + threadIdx.x;
  long e = i4 << 2;
  int n = (int)(e >> 12);
  int r = (int)(e & 4095);
  us4 o;
  if (n < 4000) {
    int s = r >> 7, d = r & 127;
    float4 v = *(const float4*)(embsL + ((long)s * 4000 + n) * 128 + d);
    o[0] = f2bf(v.x); o[1] = f2bf(v.y); o[2] = f2bf(v.z); o[3] = f2bf(v.w);
  } else { o[0] = o[1] = o[2] = o[3] = 0; }
  *(us4*)(X + (long)n * 4096 + r) = o;
}

// ---------------------------------------------------------------------------
// Attention core (scores/softmax/msum only).
// ---------------------------------------------------------------------------
__global__ __launch_bounds__(128) void attention2(const float* __restrict__ F,
                                                  const float* __restrict__ Q,
                                                  const float* __restrict__ ae,
                                                  const float* __restrict__ ab,
                                                  unsigned short* __restrict__ CATl) {
  int n = blockIdx.x, t = threadIdx.x;
  if (n >= 4000) {   // zero pad rows so the CAT GEMM stays finite
    CATl[(size_t)n * 256 + t] = 0;
    CATl[(size_t)n * 256 + 128 + t] = 0;
    return;
  }
  __shared__ float Fs[32 * 132];
  __shared__ float qv[128], attw[32], btv[32];
  const float* Fr = F + (long)n * 4096;
  for (int i = t; i < 4096; i += 128) { int s = i >> 7, d = i & 127; Fs[s * 132 + d] = Fr[i]; }
  qv[t] = Q[(long)n * 128 + t];
  __syncthreads();
  if (t < 32) {
    float sc = 0.f;
    for (int d = 0; d < 128; ++d) sc += qv[d] * Fs[t * 132 + d];
    float mx = sc;
    for (int o = 16; o; o >>= 1) mx = fmaxf(mx, __shfl_xor(mx, o, 32));
    float ex = expf(sc - mx), sm = ex;
    for (int o = 16; o; o >>= 1) sm += __shfl_xor(sm, o, 32);
    attw[t] = ex / sm;
  } else if (t >= 64 && t < 96) {
    int s = t - 64;
    btv[s] = expf(-ab[n] * (float)(31 - s));
  }
  __syncthreads();
  float aen = ae[n], acc = 0.f;
  for (int s = 0; s < 32; ++s) {
    float f = Fs[s * 132 + t];
    acc += attw[s] * (f + aen * btv[s] * fmaxf(f, 0.f));
  }
  CATl[(size_t)n * 256 + t] = f2bf(acc);
  CATl[(size_t)n * 256 + 128 + t] = f2bf(qv[t]);
}

// ---------------------------------------------------------------------------
// Final stage (all f32, deterministic reductions)
// ---------------------------------------------------------------------------
__global__ __launch_bounds__(256) void tanh_qs(const float* __restrict__ outs,
                                               const float* __restrict__ embt,
                                               float* __restrict__ T, float* __restrict__ qs) {
  long i = (long)blockIdx.x * 256 + threadIdx.x;
  if (i < 1024000) T[i] = tanhf(outs[i]);
  else { long j = i - 1024000; if (j < 512000) qs[j] = fmaxf(embt[j], 0.f); }
}

// 8-way n-chunked partials of qs^T @ tanh(outs)
__global__ __launch_bounds__(256) void betas_part(const float* __restrict__ qs,
                                                  const float* __restrict__ T,
                                                  float* __restrict__ out) {
  int e = threadIdx.x & 127, dl = threadIdx.x >> 7;
  int d = blockIdx.x * 2 + dl, l = blockIdx.y, nc = blockIdx.z;
  const float* Tl = T + (long)l * 512000;
  float acc = 0.f;
  int n0 = nc * 500;
  for (int n = n0; n < n0 + 500; ++n)
    acc += qs[(long)n * 128 + d] * Tl[(long)n * 128 + e];
  out[(long)nc * 32768 + (long)l * 16384 + d * 128 + e] = acc;
}

__global__ __launch_bounds__(256) void bnorm_kernel(const float* __restrict__ brawp,
                                                    float* __restrict__ bn) {
  int i = blockIdx.x * 256 + threadIdx.x;   // < 16384
  float s0 = 0.f, s1 = 0.f;
  for (int nc = 0; nc < 8; ++nc) {
    s0 += brawp[(long)nc * 32768 + i];
    s1 += brawp[(long)nc * 32768 + 16384 + i];
  }
  float b0 = expf(s0), b1 = expf(s1);
  float s = b0 + b1;
  bn[i] = b0 / s;
  bn[16384 + i] = b1 / s;
}

__global__ __launch_bounds__(256) void z_kernel(const float* __restrict__ outs,
                                                const float* __restrict__ bn,
                                                float* __restrict__ Zb) {
  int n = blockIdx.x * 2 + (threadIdx.x >> 7);
  int e = threadIdx.x & 127;
  float acc = 0.f;
  for (int l = 0; l < 2; ++l) {
    const float* orow = outs + ((long)l * 4000 + n) * 128;
    const float* brow = bn + (long)l * 16384;
    for (int d = 0; d < 128; ++d) acc += orow[d] * brow[d * 128 + e];
  }
  Zb[(long)n * 128 + e] = acc;
}

__global__ __launch_bounds__(256) void p_kernel(const float* __restrict__ Zb,
                                                const float* __restrict__ Wp,
                                                float* __restrict__ P) {
  int n = blockIdx.x * 4 + (threadIdx.x >> 6);
  int c = threadIdx.x & 63;
  float val = 0.f;
  if (c < 10) {
    const float* zr = Zb + (long)n * 128;
    for (int d = 0; d < 128; ++d) val += zr[d] * Wp[d * 10 + c];
  }
  float mx = val;
  for (int i = 0; i < 10; ++i) mx = fmaxf(mx, __shfl(val, i, 64));
  float ex = (c < 10) ? expf(val - mx) : 0.f;
  float sm = 0.f;
  for (int i = 0; i < 10; ++i) sm += __shfl(ex, i, 64);
  if (c < 12) P[(long)n * 12 + c] = (c < 10) ? ex / sm : 0.f;
}

__global__ __launch_bounds__(256) void ap_kernel(const float* __restrict__ A,
                                                 const float* __restrict__ P,
                                                 float* __restrict__ AP) {
  int m = blockIdx.x, t = threadIdx.x;
  const float* Ar = A + (long)m * 4000;
  float acc[10];
#pragma unroll
  for (int c = 0; c < 10; ++c) acc[c] = 0.f;
  for (int n = t; n < 4000; n += 256) {
    float a = Ar[n];
    const float* Pr = P + (long)n * 12;
#pragma unroll
    for (int c = 0; c < 10; ++c) acc[c] += a * Pr[c];
  }
#pragma unroll
  for (int c = 0; c < 10; ++c)
    for (int o = 32; o; o >>= 1) acc[c] += __shfl_xor(acc[c], o);
  __shared__ float ls[4][10];
  if ((t & 63) == 0)
    for (int c = 0; c < 10; ++c) ls[t >> 6][c] = acc[c];
  __syncthreads();
  if (t < 10) AP[(long)m * 12 + t] = ls[0][t] + ls[1][t] + ls[2][t] + ls[3][t];
  if (t >= 10 && t < 12) AP[(long)m * 12 + t] = 0.f;
}

__global__ __launch_bounds__(256) void etacm_part(const float* __restrict__ P,
                                                  const float* __restrict__ AP,
                                                  const float* __restrict__ Z,
                                                  float* __restrict__ peta,
                                                  float* __restrict__ pcm) {
  int b = blockIdx.x, t = threadIdx.x;
  int ms = b * 63, me = ms + 63; if (me > 4000) me = 4000;
  int i_ = t / 10, j_ = t % 10;
  float ea = 0.f;
  float ca[5];
#pragma unroll
  for (int k = 0; k < 5; ++k) ca[k] = 0.f;
  for (int m = ms; m < me; ++m) {
    if (t < 100) ea += P[(long)m * 12 + i_] * AP[(long)m * 12 + j_];
#pragma unroll
    for (int k = 0; k < 5; ++k) {
      int idx = t + 256 * k;
      int c = idx >> 7, e = idx & 127;
      ca[k] += P[(long)m * 12 + c] * Z[(long)m * 128 + e];
    }
  }
  if (t < 100) peta[(long)b * 100 + t] = ea;
#pragma unroll
  for (int k = 0; k < 5; ++k) pcm[(long)b * 1280 + t + 256 * k] = ca[k];
}

__global__ __launch_bounds__(256) void final_small(const float* __restrict__ peta,
                                                   const float* __restrict__ pcm,
                                                   const float* __restrict__ Wc,
                                                   float* __restrict__ cprime) {
  __shared__ float eta_s[100], cm_s[1280], tmp_s[1280];
  int t = threadIdx.x;
  if (t < 100) {
    float s = 0.f;
    for (int b = 0; b < 64; ++b) s += peta[(long)b * 100 + t];
    eta_s[t] = s;
  }
  for (int i = t; i < 1280; i += 256) {
    float s = 0.f;
    for (int b = 0; b < 64; ++b) s += pcm[(long)b * 1280 + i];
    cm_s[i] = s;
  }
  __syncthreads();
  for (int i = t; i < 1280; i += 256) {
    int c = i >> 7, d = i & 127;
    float s = 0.f;
    for (int e = 0; e < 128; ++e) s += cm_s[c * 128 + e] * Wc[d * 128 + e];
    tmp_s[i] = s;
  }
  __syncthreads();
  for (int i = t; i < 1280; i += 256) {
    int c = i >> 7, d = i & 127;
    float s = 0.f;
    for (int j = 0; j < 10; ++j) s += eta_s[c * 10 + j] * tmp_s[j * 128 + d];
    cprime[i] = fmaxf(s, 0.f);
  }
}

__global__ __launch_bounds__(256) void out_kernel(const float* __restrict__ P,
                                                  const float* __restrict__ cpr,
                                                  float* __restrict__ out) {
  int idx = blockIdx.x * 256 + threadIdx.x;  // < 512000
  int n = idx >> 7, d = idx & 127;
  float s = 0.f;
#pragma unroll
  for (int c = 0; c < 10; ++c) s += P[(long)n * 12 + c] * cpr[c * 128 + d];
  out[idx] = s;
}

// ---------------------------------------------------------------------------
extern "C" void kernel_launch(void* const* d_in, const int* in_sizes, int n_in,
                              void* d_out, int out_size, void* d_ws, size_t ws_size,
                              hipStream_t stream) {
  (void)in_sizes; (void)n_in; (void)out_size; (void)ws_size;
  const float* A      = (const float*)d_in[0];
  const float* embs   = (const float*)d_in[1];
  const float* conv1w = (const float*)d_in[2];
  const float* conv2w = (const float*)d_in[3];
  const float* lin_in = (const float*)d_in[4];
  const float* lin_out= (const float*)d_in[5];
  const float* Wpsi   = (const float*)d_in[6];
  const float* bpsi   = (const float*)d_in[7];
  const float* ae     = (const float*)d_in[8];
  const float* ab     = (const float*)d_in[9];
  const float* embt   = (const float*)d_in[10];
  const float* Wp     = (const float*)d_in[11];
  const float* Wc     = (const float*)d_in[12];
  float* out = (float*)d_out;
  char* ws = (char*)d_ws;

  size_t off = 0;
  auto alloc = [&](size_t b) { size_t r = off; off += (b + 255) & ~(size_t)255; return r; };
  unsigned short* PCAT = (unsigned short*)(ws + alloc((size_t)4096 * 8192 * 2)); // [m, k]
  char*           BTF  = ws + alloc((size_t)4096 * 8192 * 2);                    // BT bf16 / F f32 union
  unsigned short* BT   = (unsigned short*)BTF;
  float*          Ff   = (float*)BTF;
  unsigned short* XBF  = (unsigned short*)(ws + alloc((size_t)4096 * 4096 * 2)); // union PV
  unsigned short* PV   = XBF;
  unsigned short* HBUF = (unsigned short*)(ws + alloc((size_t)4096 * 4096 * 2)); // union PVT
  unsigned short* PVT  = HBUF;
  float* DIS   = (float*)(ws + alloc(4096 * 4));
  float* IWROW = (float*)(ws + alloc(4096 * 4));
  float* IWCOL = (float*)(ws + alloc(4096 * 4));
  float* WCP   = (float*)(ws + alloc((size_t)32 * 4096 * 4));
  unsigned short* CW1T = (unsigned short*)(ws + alloc(32768 * 2));
  unsigned short* CW2T = (unsigned short*)(ws + alloc(32768 * 2));
  unsigned short* WPST = (unsigned short*)(ws + alloc(32768 * 2));
  unsigned short* LWOB = (unsigned short*)(ws + alloc(32768 * 2));
  unsigned short* WQ   = (unsigned short*)(ws + alloc(32768 * 2));
  float* BQ    = (float*)(ws + alloc(128 * 4));
  float* QBUF  = (float*)(ws + alloc((size_t)4096 * 128 * 4));
  unsigned short* CAT = (unsigned short*)(ws + alloc((size_t)8192 * 256 * 2));
  float* OUTS = (float*)(ws + alloc((size_t)2 * 4000 * 128 * 4));
  float* TT   = (float*)(ws + alloc((size_t)2 * 4000 * 128 * 4));
  float* QS   = (float*)(ws + alloc((size_t)4000 * 128 * 4));
  float* BRAWP= (float*)(ws + alloc((size_t)8 * 32768 * 4));
  float* BNRM = (float*)(ws + alloc(32768 * 4));
  float* ZB   = (float*)(ws + alloc((size_t)4000 * 128 * 4));
  float* PP   = (float*)(ws + alloc((size_t)4000 * 12 * 4));
  float* APB  = (float*)(ws + alloc((size_t)4000 * 12 * 4));
  float* PETA = (float*)(ws + alloc((size_t)64 * 100 * 4));
  float* PCM  = (float*)(ws + alloc((size_t)64 * 1280 * 4));
  float* CPR  = (float*)(ws + alloc(1280 * 4));

  const int BIG = 1 << 30;

  // --- graph normalization + weight prep ---
  rowsum_dis<<<4096, 256, 0, stream>>>(A, DIS);
  wrow_kernel<<<4096, 256, 0, stream>>>(A, DIS, IWROW);
  wcol_part<<<dim3(16, 32), 256, 0, stream>>>(A, DIS, WCP);
  wcol_fin<<<16, 256, 0, stream>>>(WCP, DIS, IWCOL);
  prep_weights<<<512, 256, 0, stream>>>(lin_out, conv1w, conv2w, Wpsi,
                                        CW1T, CW2T, WPST, LWOB);
  wq_prep<<<129, 256, 0, stream>>>(lin_in, bpsi, WPST, WQ, BQ);
  build_P<<<dim3(64, 64), 256, 0, stream>>>(A, DIS, IWROW, IWCOL, PCAT, PV, PVT);

  // M2 = Pv@Pv into Pcat cols [4096,8192): storeT
  gemm256<1, 0><<<256, 512, 0, stream>>>(PVT, 4096, PV, 4096, PCAT + 4096, 8192, 4096);

  for (int l = 0; l < 2; ++l) {
    convert_X<<<16384, 256, 0, stream>>>(embs + (long)l * 32 * 4000 * 128, XBF);
    // BT1[s*128+e, w*4096+n] = (X_s @ W1w)[n,e]
    gemm_smallk<0, 128, 2><<<dim3(32, 2, 32), 256, 0, stream>>>(
        XBF, XBF, BIG, 128, 4096, CW1T, 128,
        BT, 8192L, 1L, 128L * 8192, 4096L, nullptr);
    // H1 = relu(Pcat @ BT1)
    gemm256<0, 1><<<256, 512, 0, stream>>>(PCAT, 8192, BT, 8192, HBUF, 4096, 8192);
    // BT2 from H1
    gemm_smallk<0, 128, 2><<<dim3(32, 2, 32), 256, 0, stream>>>(
        HBUF, HBUF, BIG, 128, 4096, CW2T, 128,
        BT, 8192L, 1L, 128L * 8192, 4096L, nullptr);
    // H2 = Pcat @ BT2 (no relu)
    gemm256<0, 0><<<256, 512, 0, stream>>>(PCAT, 8192, BT, 8192, HBUF, 4096, 8192);
    // fused = [0.5*H2 | 0.5*X] @ Wpsi + b, f32 into F (overwrites BT region)
    gemm_smallk<2, 256, 1><<<dim3(32, 1, 32), 256, 0, stream>>>(
        HBUF, XBF, 128, 128, 4096, WPST, 256,
        Ff, 1L, 4096L, 128L, 0L, bpsi);
    // q = [H2_s31 | X_s31] @ WQ + BQ  -> QBUF f32
    gemm_smallk<2, 256, 1><<<dim3(32, 1, 1), 256, 0, stream>>>(
        HBUF + 31 * 128, XBF + 31 * 128, 128, 0, 4096, WQ, 256,
        QBUF, 1L, 128L, 0L, 0L, BQ);
    // attention core -> CAT rows for this layer
    attention2<<<4096, 128, 0, stream>>>(Ff, QBUF, ae, ab, CAT + (size_t)l * 4096 * 256);
  }

  // OUTS = tanh(CAT @ lin_out^T), scatter to [2][4000][128]
  gemm_smallk<3, 256, 1><<<dim3(64, 1, 1), 256, 0, stream>>>(
      CAT, CAT, BIG, 0, 256, LWOB, 256,
      OUTS, 0L, 0L, 0L, 0L, nullptr);

  tanh_qs<<<6000, 256, 0, stream>>>(OUTS, embt, TT, QS);
  betas_part<<<dim3(64, 2, 8), 256, 0, stream>>>(QS, TT, BRAWP);
  bnorm_kernel<<<64, 256, 0, stream>>>(BRAWP, BNRM);
  z_kernel<<<2000, 256, 0, stream>>>(OUTS, BNRM, ZB);
  p_kernel<<<1000, 256, 0, stream>>>(ZB, Wp, PP);
  ap_kernel<<<4000, 256, 0, stream>>>(A, PP, APB);
  etacm_part<<<64, 256, 0, stream>>>(PP, APB, ZB, PETA, PCM);
  final_small<<<1, 256, 0, stream>>>(PETA, PCM, Wc, CPR);
  out_kernel<<<2000, 256, 0, stream>>>(PP, CPR, out);
}

// Round 10
// 1468.649 us; speedup vs baseline: 1.0854x; 1.0854x over previous
//
#include <hip/hip_runtime.h>
#include <hip/hip_bf16.h>

// Shapes (fixed): N=4000, S=32, D=128, L=2, C=10, K=2, THETA=0.5
// Padded: NP=4096 nodes, SD=4096 (=S*D), KBIG=8192 (=2*NP)

typedef __attribute__((ext_vector_type(8))) short short8;
typedef __attribute__((ext_vector_type(4))) float f32x4;
typedef __attribute__((ext_vector_type(4))) unsigned short us4;

__device__ __forceinline__ unsigned short f2bf(float x) {
  unsigned int u = __builtin_bit_cast(unsigned int, x);
  u += 0x7FFFu + ((u >> 16) & 1u);   // RNE
  return (unsigned short)(u >> 16);
}
__device__ __forceinline__ float bf2f(unsigned short u) {
  unsigned int x = ((unsigned int)u) << 16;
  return __builtin_bit_cast(float, x);
}

__device__ __forceinline__ void gload16(const void* g, void* l) {
  __builtin_amdgcn_global_load_lds((const __attribute__((address_space(1))) void*)g,
                                   (__attribute__((address_space(3))) void*)l, 16, 0, 0);
}

__device__ __forceinline__ void barrier_() {
  __builtin_amdgcn_sched_barrier(0);
  asm volatile("" ::: "memory");
  __builtin_amdgcn_s_barrier();
  asm volatile("" ::: "memory");
  __builtin_amdgcn_sched_barrier(0);
}

// ---------------------------------------------------------------------------
// 256x256 4-phase/K-tile NT GEMM — R6 core (best measured: 237us @ K=8192,
// MfmaUtil 50.5%, 0 bank conflicts). K-LOOP FROZEN. Only the TRANS epilogue
// changed: coalesced store via LDS round-trip (old: 8B scatter @16KB stride).
// ---------------------------------------------------------------------------
template<int TRANS, int RELU>
__global__ __launch_bounds__(512, 2)
void gemm256(const unsigned short* __restrict__ Ap, int lda,
             const unsigned short* __restrict__ Bp, int ldb,
             unsigned short* __restrict__ outp, int ldo, int K)
{
  __shared__ alignas(16) unsigned short lds[81920];   // 160 KiB
  const int t = threadIdx.x;
  const int lane = t & 63;
  const int wave = t >> 6;          // 0..7
  const int wm = wave >> 2;         // 0..1
  const int wn = wave & 3;          // 0..3
  const int lrow = lane & 15;
  const int kgrp = lane >> 4;       // 0..3
  const int slotbase = (kgrp ^ (lrow & 7)) << 3;   // ushort units

  const int b = blockIdx.x;
  const int wg = (b & 7) * 32 + (b >> 3);
  const int m0 = (wg >> 4) << 8;
  const int j0 = (wg & 15) << 8;

  const int prow = t >> 3;
  const int lslot = (t & 7) ^ (prow & 7);
  const unsigned short* srcA = Ap + (size_t)(m0 + prow) * lda + lslot * 8;
  const unsigned short* srcB = Bp + (size_t)(j0 + prow) * ldb + lslot * 8;
  const size_t a64 = (size_t)64 * lda, a128 = (size_t)128 * lda;
  const size_t b64 = (size_t)64 * ldb, b128 = (size_t)128 * ldb;
  unsigned short* dA = &lds[t * 8];                 // A region: [2][16384]
  unsigned short* dB = &lds[32768 + t * 8];         // B region: [3][16384]
  const int NT = K >> 6;

#define STG_A(h, kb, kt) { const unsigned short* s_ = srcA + (h)*a128 + (size_t)(kt)*64; \
    gload16(s_, dA + (kb)*16384 + (h)*8192); \
    gload16(s_ + a64, dA + (kb)*16384 + (h)*8192 + 4096); }
#define STG_B(h, bb, kt) { const unsigned short* s_ = srcB + (h)*b128 + (size_t)(kt)*64; \
    gload16(s_, dB + (bb)*16384 + (h)*8192); \
    gload16(s_ + b64, dB + (bb)*16384 + (h)*8192 + 4096); }

  const int arb = wm * 8192 + lrow * 64 + slotbase;
  const int brb = (wn >> 1) * 8192 + ((wn & 1) << 12) + lrow * 64 + slotbase;

#define RD_A(dst, base_off) \
  _Pragma("unroll") for (int mf_ = 0; mf_ < 4; ++mf_) { \
    dst[mf_][0] = *(const short8*)&lds[(base_off) + mf_*1024]; \
    dst[mf_][1] = *(const short8*)&lds[((base_off) ^ 32) + mf_*1024]; }
#define RD_B(dst, base_off) \
  _Pragma("unroll") for (int nf_ = 0; nf_ < 2; ++nf_) { \
    dst[nf_][0] = *(const short8*)&lds[(base_off) + nf_*1024]; \
    dst[nf_][1] = *(const short8*)&lds[((base_off) ^ 32) + nf_*1024]; }

#define MFMA16(AF, BF, MB, NB) \
  _Pragma("unroll") for (int mf_ = 0; mf_ < 4; ++mf_) \
  _Pragma("unroll") for (int nf_ = 0; nf_ < 2; ++nf_) { \
    acc[(MB)+mf_][(NB)+nf_] = __builtin_amdgcn_mfma_f32_16x16x32_bf16(AF[mf_][0], BF[nf_][0], acc[(MB)+mf_][(NB)+nf_], 0,0,0); \
    acc[(MB)+mf_][(NB)+nf_] = __builtin_amdgcn_mfma_f32_16x16x32_bf16(AF[mf_][1], BF[nf_][1], acc[(MB)+mf_][(NB)+nf_], 0,0,0); }

#define LGKM(n) { asm volatile("s_waitcnt lgkmcnt(" #n ")" ::: "memory"); \
                  __builtin_amdgcn_sched_barrier(0); }

  f32x4 acc[8][4];
#pragma unroll
  for (int i = 0; i < 8; ++i)
#pragma unroll
    for (int j = 0; j < 4; ++j) acc[i][j] = f32x4{0.f, 0.f, 0.f, 0.f};

  short8 a0[4][2], a1[4][2], b0[2][2], b1[2][2];

  STG_B(0, 0, 0); STG_B(1, 0, 0); STG_A(0, 0, 0); STG_A(1, 0, 0);
  STG_B(0, 1, 1); STG_B(1, 1, 1); STG_A(0, 1, 1); STG_A(1, 1, 1);
  asm volatile("s_waitcnt vmcnt(8)" ::: "memory");
  barrier_();
  RD_A(a0, arb);
  RD_B(b0, 32768 + brb);

  int rb3 = 0, rn3 = 1, sb3 = 2;
  for (int V = 0; V < NT; ++V) {
    const int abuf  = (V & 1) << 14;
    const int anbuf = ((V + 1) & 1) << 14;
    const int bbuf  = 32768 + (rb3 << 14);
    const int bnbuf = 32768 + (rn3 << 14);
    const bool stg = (V + 2 < NT);
    const bool rdn = (V + 1 < NT);

    RD_B(b1, bbuf + brb + 2048);
    LGKM(4);
    if (stg) STG_B(0, sb3, V + 2);
    __builtin_amdgcn_s_setprio(1);
    MFMA16(a0, b0, 0, 0);
    __builtin_amdgcn_s_setprio(0);
    barrier_();

    RD_A(a1, abuf + arb + 4096);
    LGKM(8);
    if (stg) STG_B(1, sb3, V + 2);
    __builtin_amdgcn_s_setprio(1);
    MFMA16(a0, b1, 0, 2);
    __builtin_amdgcn_s_setprio(0);
    if (stg) { asm volatile("s_waitcnt vmcnt(4)" ::: "memory"); }
    else     { asm volatile("s_waitcnt vmcnt(0)" ::: "memory"); }
    barrier_();

    if (rdn) { RD_A(a0, anbuf + arb); LGKM(8); }
    else     { LGKM(0); }
    if (stg) STG_A(0, (V & 1), V + 2);
    __builtin_amdgcn_s_setprio(1);
    MFMA16(a1, b0, 4, 0);
    __builtin_amdgcn_s_setprio(0);
    barrier_();

    if (rdn) { RD_B(b0, bnbuf + brb); LGKM(4); }
    else     { LGKM(0); }
    if (stg) STG_A(1, (V & 1), V + 2);
    __builtin_amdgcn_s_setprio(1);
    MFMA16(a1, b1, 4, 2);
    __builtin_amdgcn_s_setprio(0);
    barrier_();

    rb3 = rn3; rn3 = (rn3 == 2) ? 0 : rn3 + 1;
    sb3 = (sb3 == 2) ? 0 : sb3 + 1;
  }

  // epilogue: C/D layout col=lane&15, row=(lane>>4)*4+r
  if (TRANS) {
    // coalesced C^T store via LDS round-trip (K-loop's final barrier already
    // guarantees all LDS reads drained; safe to overwrite).
    // pack: LDS[j_local][256 us] with us4-group swizzle gm ^= (j&7)
#pragma unroll
    for (int mf = 0; mf < 8; ++mf) {
#pragma unroll
      for (int nf = 0; nf < 4; ++nf) {
        const int ml = wm * 128 + mf * 16 + kgrp * 4;
        const int jl = wn * 64 + nf * 16 + lrow;
        const int gm = ml >> 2;
        us4 pk;
#pragma unroll
        for (int r = 0; r < 4; ++r) pk[r] = f2bf(acc[mf][nf][r]);
        *(us4*)&lds[jl * 256 + ((gm ^ (jl & 7)) << 2)] = pk;
      }
    }
    barrier_();
#pragma unroll
    for (int i = 0; i < 32; ++i) {
      const int r = i * 8 + (t >> 6);
      const int c = t & 63;
      us4 v = *(const us4*)&lds[r * 256 + ((c ^ (r & 7)) << 2)];
      *(us4*)(outp + (size_t)(j0 + r) * ldo + m0 + c * 4) = v;
    }
  } else {
#pragma unroll
    for (int mf = 0; mf < 8; ++mf) {
#pragma unroll
      for (int nf = 0; nf < 4; ++nf) {
        const int m = m0 + wm * 128 + mf * 16 + kgrp * 4;
        const int j = j0 + wn * 64 + nf * 16 + lrow;
#pragma unroll
        for (int r = 0; r < 4; ++r) {
          float v = acc[mf][nf][r];
          if (RELU) v = fmaxf(v, 0.f);
          outp[(size_t)(m + r) * ldo + j] = f2bf(v);
        }
      }
    }
  }
#undef STG_A
#undef STG_B
#undef RD_A
#undef RD_B
#undef MFMA16
#undef LGKM
}

// ---------------------------------------------------------------------------
// Small-K NT GEMM: stage the ENTIRE K (<=256) upfront, ONE barrier, all MFMAs.
// 128x128 tile, 4 waves (2x2), 4x4 frags.
// EPI 0: transposed bf16 store — NOW coalesced via LDS round-trip (reuses At).
// EPI 2: f32 + bias (Z32: z==32 computes the q-projection: B2/out2/bias2).
// EPI 3: tanh f32 scatter to OUTS + TT = tanh(tanh) into out2.
// ---------------------------------------------------------------------------
template<int EPI, int KFULL, int MINB, int Z32>
__global__ __launch_bounds__(256, MINB)
void gemm_smallk(const unsigned short* __restrict__ A1,
                 const unsigned short* __restrict__ A2,
                 int k_switch, int a_zstride, int lda,
                 const unsigned short* __restrict__ B, int ldb,
                 void* __restrict__ outp,
                 long o_j, long o_m, long o_z, long o_jt,
                 const float* __restrict__ bias,
                 const unsigned short* __restrict__ B2,
                 float* __restrict__ out2,
                 const float* __restrict__ bias2)
{
  __shared__ alignas(16) unsigned short At[(KFULL / 32) * 4096];
  __shared__ alignas(16) unsigned short Bt[(KFULL / 32) * 4096];
  const int t = threadIdx.x;
  const int lane = t & 63;
  const int wave = t >> 6;
  const int m0 = blockIdx.x << 7;
  const int jt = blockIdx.y;
  const int j0 = jt << 7;
  const int z  = blockIdx.z;
  const bool isq = Z32 && (z == 32);
  const int ze = isq ? 31 : z;
  const unsigned short* Bp = isq ? B2 : B;
  const int wm = (wave >> 1) << 6;
  const int wn = (wave & 1) << 6;
  const int lrow = lane & 15;
  const int kgrp = lane >> 4;

  const unsigned short* A1z = A1 + (long)ze * a_zstride;
  const unsigned short* A2z = A2 + (long)ze * a_zstride;

  const int r0 = t >> 2, q0 = t & 3;
  const int c1 = t + 256;
  const int r1 = c1 >> 2, q1 = c1 & 3;

#pragma unroll
  for (int kk = 0; kk < KFULL / 32; ++kk) {
    const int k0 = kk * 32;
    const unsigned short* As; int ka;
    if (k0 < k_switch) { As = A1z; ka = k0; } else { As = A2z; ka = k0 - k_switch; }
    gload16(As + (long)(m0 + r0) * lda + ka + q0 * 8, At + kk * 4096 + t * 8);
    gload16(As + (long)(m0 + r1) * lda + ka + q1 * 8, At + kk * 4096 + c1 * 8);
    gload16(Bp + (long)(j0 + r0) * ldb + k0 + q0 * 8, Bt + kk * 4096 + t * 8);
    gload16(Bp + (long)(j0 + r1) * ldb + k0 + q1 * 8, Bt + kk * 4096 + c1 * 8);
  }
  __syncthreads();   // drains vmcnt(0)

  f32x4 acc[4][4];
#pragma unroll
  for (int i = 0; i < 4; ++i)
#pragma unroll
    for (int j = 0; j < 4; ++j) acc[i][j] = f32x4{0.f, 0.f, 0.f, 0.f};

#pragma unroll
  for (int kk = 0; kk < KFULL / 32; ++kk) {
    short8 af[4], bv[4];
#pragma unroll
    for (int i = 0; i < 4; ++i)
      af[i] = *(const short8*)(At + kk * 4096 + (wm + i * 16 + lrow) * 32 + kgrp * 8);
#pragma unroll
    for (int i = 0; i < 4; ++i)
      bv[i] = *(const short8*)(Bt + kk * 4096 + (wn + i * 16 + lrow) * 32 + kgrp * 8);
#pragma unroll
    for (int i = 0; i < 4; ++i)
#pragma unroll
      for (int j = 0; j < 4; ++j)
        acc[i][j] = __builtin_amdgcn_mfma_f32_16x16x32_bf16(af[i], bv[j], acc[i][j], 0, 0, 0);
  }

  const int mlb = wm + kgrp * 4;
  if (EPI == 0) {
    // coalesced transposed store: pack acc -> At as [jl][128 us] (swizzled),
    // then row-major coalesced us4 stores.
    __syncthreads();   // all waves done reading At/Bt
#pragma unroll
    for (int i = 0; i < 4; ++i) {
#pragma unroll
      for (int j = 0; j < 4; ++j) {
        const int jl = wn + j * 16 + lrow;
        const int ml = mlb + i * 16;
        const int gm = ml >> 2;
        us4 pk;
#pragma unroll
        for (int r = 0; r < 4; ++r) pk[r] = f2bf(acc[i][j][r]);
        *(us4*)&At[jl * 128 + ((gm ^ (jl & 7)) << 2)] = pk;
      }
    }
    __syncthreads();
#pragma unroll
    for (int i = 0; i < 16; ++i) {
      const int r = i * 8 + (t >> 5);
      const int c = t & 31;
      us4 v = *(const us4*)&At[r * 128 + ((c ^ (r & 7)) << 2)];
      long base = (long)r * o_j + (long)(m0 + c * 4) * o_m + (long)z * o_z + (long)jt * o_jt;
      *(us4*)((unsigned short*)outp + base) = v;
    }
    return;
  }

#pragma unroll
  for (int i = 0; i < 4; ++i) {
#pragma unroll
    for (int j = 0; j < 4; ++j) {
      const int jl = wn + j * 16 + lrow;
      const int ml = mlb + i * 16;
      if (EPI == 2) {
        if (isq) {
          float badd = bias2[j0 + jl];
#pragma unroll
          for (int r = 0; r < 4; ++r)
            out2[(size_t)(m0 + ml + r) * 128 + (j0 + jl)] = acc[i][j][r] + badd;
        } else {
          float* of = (float*)outp;
          float badd = bias[j0 + jl];
#pragma unroll
          for (int r = 0; r < 4; ++r) {
            long idx = (long)jl * o_j + (long)(m0 + ml + r) * o_m + (long)z * o_z + (long)jt * o_jt;
            of[idx] = acc[i][j][r] + badd;
          }
        }
      } else {   // EPI == 3: tanh scatter to OUTS + TT
        float* of = (float*)outp;
#pragma unroll
        for (int r = 0; r < 4; ++r) {
          int mm = m0 + ml + r;
          int n = mm & 4095, l = mm >> 12;
          if (n < 4000) {
            float o = tanhf(acc[i][j][r]);
            size_t idx = (size_t)l * 512000 + (size_t)n * 128 + (j0 + jl);
            of[idx] = o;
            out2[idx] = tanhf(o);
          }
        }
      }
    }
  }
}

// ---------------------------------------------------------------------------
// Graph-normalization prep
// ---------------------------------------------------------------------------
__global__ __launch_bounds__(256) void rowsum_dis(const float* __restrict__ A,
                                                  float* __restrict__ dis) {
  int m = blockIdx.x;
  if (m >= 4000) { if (threadIdx.x == 0) dis[m] = 0.f; return; }
  const float* r = A + (long)m * 4000;
  float a = 0.f;
  for (int i = threadIdx.x; i < 1000; i += 256) {
    float4 v = ((const float4*)r)[i];
    a += v.x + v.y + v.z + v.w;
  }
  for (int o = 32; o; o >>= 1) a += __shfl_xor(a, o);
  __shared__ float ls[4];
  if ((threadIdx.x & 63) == 0) ls[threadIdx.x >> 6] = a;
  __syncthreads();
  if (threadIdx.x == 0) dis[m] = rsqrtf(1.f + ls[0] + ls[1] + ls[2] + ls[3]);
}

__global__ __launch_bounds__(256) void wrow_kernel(const float* __restrict__ A,
                                                   const float* __restrict__ dis,
                                                   float* __restrict__ iwrow) {
  int m = blockIdx.x;
  if (m >= 4000) { if (threadIdx.x == 0) iwrow[m] = 0.f; return; }
  const float* r = A + (long)m * 4000;
  float a = 0.f;
  for (int n = threadIdx.x; n < 4000; n += 256) a += r[n] * dis[n];
  for (int o = 32; o; o >>= 1) a += __shfl_xor(a, o);
  __shared__ float ls[4];
  if ((threadIdx.x & 63) == 0) ls[threadIdx.x >> 6] = a;
  __syncthreads();
  if (threadIdx.x == 0) iwrow[m] = 1.f / (ls[0] + ls[1] + ls[2] + ls[3] + dis[m]);
}

__global__ __launch_bounds__(256) void wcol_part(const float* __restrict__ A,
                                                 const float* __restrict__ dis,
                                                 float* __restrict__ part) {
  int j = blockIdx.x * 256 + threadIdx.x;   // 0..4095
  int mz = blockIdx.y;                      // 0..31
  float a = 0.f;
  if (j < 4000) {
    int ms = mz * 125;
    for (int m = ms; m < ms + 125; ++m) a += A[(long)m * 4000 + j] * dis[m];
  }
  part[(long)mz * 4096 + j] = a;
}

__global__ __launch_bounds__(256) void wcol_fin(const float* __restrict__ part,
                                                const float* __restrict__ dis,
                                                float* __restrict__ iwcol) {
  int j = blockIdx.x * 256 + threadIdx.x;
  float s = 0.f;
  for (int z = 0; z < 32; ++z) s += part[(long)z * 4096 + j];
  iwcol[j] = (j < 4000) ? 1.f / (s + dis[j]) : 0.f;
}

// P_f into Pcat cols [0,4096); P_vT and P_v (transposed via LDS) separately.
__global__ __launch_bounds__(256) void build_P(const float* __restrict__ A,
                                               const float* __restrict__ dis,
                                               const float* __restrict__ iwrow,
                                               const float* __restrict__ iwcol,
                                               unsigned short* __restrict__ Pcat,
                                               unsigned short* __restrict__ PV,
                                               unsigned short* __restrict__ PVT) {
  __shared__ float tile[64][65];
  int m0 = blockIdx.y * 64, n0 = blockIdx.x * 64;
#pragma unroll
  for (int i = 0; i < 16; ++i) {
    int idx = i * 256 + threadIdx.x;
    int lr = idx >> 6, lc = idx & 63;
    int m = m0 + lr, n = n0 + lc;
    float v = 0.f;
    if (m < 4000 && n < 4000) {
      float a = A[(long)m * 4000 + n];
      if (m == n) a += 1.f;
      v = a * dis[n];
    }
    Pcat[(long)m * 8192 + n] = f2bf(v * iwrow[m]);
    float pv = v * iwcol[m];
    PVT[(long)m * 4096 + n] = f2bf(pv);
    tile[lr][lc] = pv;
  }
  __syncthreads();
#pragma unroll
  for (int i = 0; i < 16; ++i) {
    int idx = i * 256 + threadIdx.x;
    int lr = idx >> 6, lc = idx & 63;
    PV[(long)(n0 + lr) * 4096 + (m0 + lc)] = f2bf(tile[lc][lr]);
  }
}

// Small-weight transposes + qs = relu(emb_table) (one-time)
__global__ __launch_bounds__(256) void prep_weights(const float* __restrict__ lin_out,
                                                    const float* __restrict__ c1,
                                                    const float* __restrict__ c2,
                                                    const float* __restrict__ wpsi,
                                                    const float* __restrict__ embt,
                                                    unsigned short* __restrict__ CW1T,
                                                    unsigned short* __restrict__ CW2T,
                                                    unsigned short* __restrict__ WPST,
                                                    unsigned short* __restrict__ LWOB,
                                                    float* __restrict__ qs) {
  int i = blockIdx.x * 256 + threadIdx.x;
  if (i < 32768) {
    int j = i >> 7, kk = i & 127;
    CW1T[i] = f2bf(c1[(j >> 7) * 16384 + kk * 128 + (j & 127)]);
  } else if (i < 65536) {
    int k = i - 32768; int j = k >> 7, kk = k & 127;
    CW2T[k] = f2bf(c2[(j >> 7) * 16384 + kk * 128 + (j & 127)]);
  } else if (i < 98304) {
    int k = i - 65536; int e = k >> 8, d2 = k & 255;
    WPST[k] = f2bf(0.5f * wpsi[d2 * 128 + e]);
  } else if (i < 131072) {
    int k = i - 98304;
    LWOB[k] = f2bf(lin_out[k]);
  } else if (i < 643072) {
    int k = i - 131072;
    qs[k] = fmaxf(embt[k], 0.f);
  }
}

// WQ[d*256+k2] = sum_e lin_in[d*128+e] * WPST[e*256+k2]  (bf16 out)
// BQ[d] = sum_e bpsi[e] * lin_in[d*128+e]
__global__ __launch_bounds__(256) void wq_prep(const float* __restrict__ lin_in,
                                               const float* __restrict__ bpsi,
                                               const unsigned short* __restrict__ WPST,
                                               unsigned short* __restrict__ WQ,
                                               float* __restrict__ BQ) {
  int b = blockIdx.x, t = threadIdx.x;
  if (b < 128) {
    int idx = b * 256 + t;
    int d = idx >> 8, k2 = idx & 255;
    float acc = 0.f;
    for (int e = 0; e < 128; ++e)
      acc += lin_in[d * 128 + e] * bf2f(WPST[e * 256 + k2]);
    WQ[idx] = f2bf(acc);
  } else if (t < 128) {
    float acc = 0.f;
    for (int e = 0; e < 128; ++e) acc += bpsi[e] * lin_in[t * 128 + e];
    BQ[t] = acc;
  }
}

// embs[l] (S,N,D) -> X_bf (NP, S*D) bf16, pad rows zeroed
__global__ __launch_bounds__(256) void convert_X(const float* __restrict__ embsL,
                                                 unsigned short* __restrict__ X) {
  long i4 = (long)blockIdx.x * 256 + threadIdx.x;
  long e = i4 << 2;
  int n = (int)(e >> 12);
  int r = (int)(e & 4095);
  us4 o;
  if (n < 4000) {
    int s = r >> 7, d = r & 127;
    float4 v = *(const float4*)(embsL + ((long)s * 4000 + n) * 128 + d);
    o[0] = f2bf(v.x); o[1] = f2bf(v.y); o[2] = f2bf(v.z); o[3] = f2bf(v.w);
  } else { o[0] = o[1] = o[2] = o[3] = 0; }
  *(us4*)(X + (long)n * 4096 + r) = o;
}

// ---------------------------------------------------------------------------
// Attention core (scores/softmax/msum only).
// ---------------------------------------------------------------------------
__global__ __launch_bounds__(128) void attention2(const float* __restrict__ F,
                                                  const float* __restrict__ Q,
                                                  const float* __restrict__ ae,
                                                  const float* __restrict__ ab,
                                                  unsigned short* __restrict__ CATl) {
  int n = blockIdx.x, t = threadIdx.x;
  if (n >= 4000) {   // zero pad rows so the CAT GEMM stays finite
    CATl[(size_t)n * 256 + t] = 0;
    CATl[(size_t)n * 256 + 128 + t] = 0;
    return;
  }
  __shared__ float Fs[32 * 132];
  __shared__ float qv[128], attw[32], btv[32];
  const float* Fr = F + (long)n * 4096;
  for (int i = t; i < 4096; i += 128) { int s = i >> 7, d = i & 127; Fs[s * 132 + d] = Fr[i]; }
  qv[t] = Q[(long)n * 128 + t];
  __syncthreads();
  if (t < 32) {
    float sc = 0.f;
    for (int d = 0; d < 128; ++d) sc += qv[d] * Fs[t * 132 + d];
    float mx = sc;
    for (int o = 16; o; o >>= 1) mx = fmaxf(mx, __shfl_xor(mx, o, 32));
    float ex = expf(sc - mx), sm = ex;
    for (int o = 16; o; o >>= 1) sm += __shfl_xor(sm, o, 32);
    attw[t] = ex / sm;
  } else if (t >= 64 && t < 96) {
    int s = t - 64;
    btv[s] = expf(-ab[n] * (float)(31 - s));
  }
  __syncthreads();
  float aen = ae[n], acc = 0.f;
  for (int s = 0; s < 32; ++s) {
    float f = Fs[s * 132 + t];
    acc += attw[s] * (f + aen * btv[s] * fmaxf(f, 0.f));
  }
  CATl[(size_t)n * 256 + t] = f2bf(acc);
  CATl[(size_t)n * 256 + 128 + t] = f2bf(qv[t]);
}

// ---------------------------------------------------------------------------
// Final stage (all f32, deterministic reductions)
// ---------------------------------------------------------------------------
// 8-way n-chunked partials of qs^T @ tanh(outs)
__global__ __launch_bounds__(256) void betas_part(const float* __restrict__ qs,
                                                  const float* __restrict__ T,
                                                  float* __restrict__ out) {
  int e = threadIdx.x & 127, dl = threadIdx.x >> 7;
  int d = blockIdx.x * 2 + dl, l = blockIdx.y, nc = blockIdx.z;
  const float* Tl = T + (long)l * 512000;
  float acc = 0.f;
  int n0 = nc * 500;
  for (int n = n0; n < n0 + 500; ++n)
    acc += qs[(long)n * 128 + d] * Tl[(long)n * 128 + e];
  out[(long)nc * 32768 + (long)l * 16384 + d * 128 + e] = acc;
}

__global__ __launch_bounds__(256) void bnorm_kernel(const float* __restrict__ brawp,
                                                    float* __restrict__ bn) {
  int i = blockIdx.x * 256 + threadIdx.x;   // < 16384
  float s0 = 0.f, s1 = 0.f;
  for (int nc = 0; nc < 8; ++nc) {
    s0 += brawp[(long)nc * 32768 + i];
    s1 += brawp[(long)nc * 32768 + 16384 + i];
  }
  float b0 = expf(s0), b1 = expf(s1);
  float s = b0 + b1;
  bn[i] = b0 / s;
  bn[16384 + i] = b1 / s;
}

__global__ __launch_bounds__(256) void z_kernel(const float* __restrict__ outs,
                                                const float* __restrict__ bn,
                                                float* __restrict__ Zb) {
  int n = blockIdx.x * 2 + (threadIdx.x >> 7);
  int e = threadIdx.x & 127;
  float acc = 0.f;
  for (int l = 0; l < 2; ++l) {
    const float* orow = outs + ((long)l * 4000 + n) * 128;
    const float* brow = bn + (long)l * 16384;
    for (int d = 0; d < 128; ++d) acc += orow[d] * brow[d * 128 + e];
  }
  Zb[(long)n * 128 + e] = acc;
}

__global__ __launch_bounds__(256) void p_kernel(const float* __restrict__ Zb,
                                                const float* __restrict__ Wp,
                                                float* __restrict__ P) {
  int n = blockIdx.x * 4 + (threadIdx.x >> 6);
  int c = threadIdx.x & 63;
  float val = 0.f;
  if (c < 10) {
    const float* zr = Zb + (long)n * 128;
    for (int d = 0; d < 128; ++d) val += zr[d] * Wp[d * 10 + c];
  }
  float mx = val;
  for (int i = 0; i < 10; ++i) mx = fmaxf(mx, __shfl(val, i, 64));
  float ex = (c < 10) ? expf(val - mx) : 0.f;
  float sm = 0.f;
  for (int i = 0; i < 10; ++i) sm += __shfl(ex, i, 64);
  if (c < 12) P[(long)n * 12 + c] = (c < 10) ? ex / sm : 0.f;
}

__global__ __launch_bounds__(256) void ap_kernel(const float* __restrict__ A,
                                                 const float* __restrict__ P,
                                                 float* __restrict__ AP) {
  int m = blockIdx.x, t = threadIdx.x;
  const float* Ar = A + (long)m * 4000;
  float acc[10];
#pragma unroll
  for (int c = 0; c < 10; ++c) acc[c] = 0.f;
  for (int n = t; n < 4000; n += 256) {
    float a = Ar[n];
    const float* Pr = P + (long)n * 12;
#pragma unroll
    for (int c = 0; c < 10; ++c) acc[c] += a * Pr[c];
  }
#pragma unroll
  for (int c = 0; c < 10; ++c)
    for (int o = 32; o; o >>= 1) acc[c] += __shfl_xor(acc[c], o);
  __shared__ float ls[4][10];
  if ((t & 63) == 0)
    for (int c = 0; c < 10; ++c) ls[t >> 6][c] = acc[c];
  __syncthreads();
  if (t < 10) AP[(long)m * 12 + t] = ls[0][t] + ls[1][t] + ls[2][t] + ls[3][t];
  if (t >= 10 && t < 12) AP[(long)m * 12 + t] = 0.f;
}

__global__ __launch_bounds__(256) void etacm_part(const float* __restrict__ P,
                                                  const float* __restrict__ AP,
                                                  const float* __restrict__ Z,
                                                  float* __restrict__ peta,
                                                  float* __restrict__ pcm) {
  int b = blockIdx.x, t = threadIdx.x;
  int ms = b * 63, me = ms + 63; if (me > 4000) me = 4000;
  int i_ = t / 10, j_ = t % 10;
  float ea = 0.f;
  float ca[5];
#pragma unroll
  for (int k = 0; k < 5; ++k) ca[k] = 0.f;
  for (int m = ms; m < me; ++m) {
    if (t < 100) ea += P[(long)m * 12 + i_] * AP[(long)m * 12 + j_];
#pragma unroll
    for (int k = 0; k < 5; ++k) {
      int idx = t + 256 * k;
      int c = idx >> 7, e = idx & 127;
      ca[k] += P[(long)m * 12 + c] * Z[(long)m * 128 + e];
    }
  }
  if (t < 100) peta[(long)b * 100 + t] = ea;
#pragma unroll
  for (int k = 0; k < 5; ++k) pcm[(long)b * 1280 + t + 256 * k] = ca[k];
}

__global__ __launch_bounds__(256) void final_small(const float* __restrict__ peta,
                                                   const float* __restrict__ pcm,
                                                   const float* __restrict__ Wc,
                                                   float* __restrict__ cprime) {
  __shared__ float eta_s[100], cm_s[1280], tmp_s[1280];
  int t = threadIdx.x;
  if (t < 100) {
    float s = 0.f;
    for (int b = 0; b < 64; ++b) s += peta[(long)b * 100 + t];
    eta_s[t] = s;
  }
  for (int i = t; i < 1280; i += 256) {
    float s = 0.f;
    for (int b = 0; b < 64; ++b) s += pcm[(long)b * 1280 + i];
    cm_s[i] = s;
  }
  __syncthreads();
  for (int i = t; i < 1280; i += 256) {
    int c = i >> 7, d = i & 127;
    float s = 0.f;
    for (int e = 0; e < 128; ++e) s += cm_s[c * 128 + e] * Wc[d * 128 + e];
    tmp_s[i] = s;
  }
  __syncthreads();
  for (int i = t; i < 1280; i += 256) {
    int c = i >> 7, d = i & 127;
    float s = 0.f;
    for (int j = 0; j < 10; ++j) s += eta_s[c * 10 + j] * tmp_s[j * 128 + d];
    cprime[i] = fmaxf(s, 0.f);
  }
}

__global__ __launch_bounds__(256) void out_kernel(const float* __restrict__ P,
                                                  const float* __restrict__ cpr,
                                                  float* __restrict__ out) {
  int idx = blockIdx.x * 256 + threadIdx.x;  // < 512000
  int n = idx >> 7, d = idx & 127;
  float s = 0.f;
#pragma unroll
  for (int c = 0; c < 10; ++c) s += P[(long)n * 12 + c] * cpr[c * 128 + d];
  out[idx] = s;
}

// ---------------------------------------------------------------------------
extern "C" void kernel_launch(void* const* d_in, const int* in_sizes, int n_in,
                              void* d_out, int out_size, void* d_ws, size_t ws_size,
                              hipStream_t stream) {
  (void)in_sizes; (void)n_in; (void)out_size; (void)ws_size;
  const float* A      = (const float*)d_in[0];
  const float* embs   = (const float*)d_in[1];
  const float* conv1w = (const float*)d_in[2];
  const float* conv2w = (const float*)d_in[3];
  const float* lin_in = (const float*)d_in[4];
  const float* lin_out= (const float*)d_in[5];
  const float* Wpsi   = (const float*)d_in[6];
  const float* bpsi   = (const float*)d_in[7];
  const float* ae     = (const float*)d_in[8];
  const float* ab     = (const float*)d_in[9];
  const float* embt   = (const float*)d_in[10];
  const float* Wp     = (const float*)d_in[11];
  const float* Wc     = (const float*)d_in[12];
  float* out = (float*)d_out;
  char* ws = (char*)d_ws;

  size_t off = 0;
  auto alloc = [&](size_t b) { size_t r = off; off += (b + 255) & ~(size_t)255; return r; };
  unsigned short* PCAT = (unsigned short*)(ws + alloc((size_t)4096 * 8192 * 2)); // [m, k]
  char*           BTF  = ws + alloc((size_t)4096 * 8192 * 2);                    // BT bf16 / F f32 union
  unsigned short* BT   = (unsigned short*)BTF;
  float*          Ff   = (float*)BTF;
  unsigned short* XBF  = (unsigned short*)(ws + alloc((size_t)4096 * 4096 * 2)); // union PV
  unsigned short* PV   = XBF;
  unsigned short* HBUF = (unsigned short*)(ws + alloc((size_t)4096 * 4096 * 2)); // union PVT
  unsigned short* PVT  = HBUF;
  float* DIS   = (float*)(ws + alloc(4096 * 4));
  float* IWROW = (float*)(ws + alloc(4096 * 4));
  float* IWCOL = (float*)(ws + alloc(4096 * 4));
  float* WCP   = (float*)(ws + alloc((size_t)32 * 4096 * 4));
  unsigned short* CW1T = (unsigned short*)(ws + alloc(32768 * 2));
  unsigned short* CW2T = (unsigned short*)(ws + alloc(32768 * 2));
  unsigned short* WPST = (unsigned short*)(ws + alloc(32768 * 2));
  unsigned short* LWOB = (unsigned short*)(ws + alloc(32768 * 2));
  unsigned short* WQ   = (unsigned short*)(ws + alloc(32768 * 2));
  float* BQ    = (float*)(ws + alloc(128 * 4));
  float* QBUF  = (float*)(ws + alloc((size_t)4096 * 128 * 4));
  unsigned short* CAT = (unsigned short*)(ws + alloc((size_t)8192 * 256 * 2));
  float* OUTS = (float*)(ws + alloc((size_t)2 * 4000 * 128 * 4));
  float* TT   = (float*)(ws + alloc((size_t)2 * 4000 * 128 * 4));
  float* QS   = (float*)(ws + alloc((size_t)4000 * 128 * 4));
  float* BRAWP= (float*)(ws + alloc((size_t)8 * 32768 * 4));
  float* BNRM = (float*)(ws + alloc(32768 * 4));
  float* ZB   = (float*)(ws + alloc((size_t)4000 * 128 * 4));
  float* PP   = (float*)(ws + alloc((size_t)4000 * 12 * 4));
  float* APB  = (float*)(ws + alloc((size_t)4000 * 12 * 4));
  float* PETA = (float*)(ws + alloc((size_t)64 * 100 * 4));
  float* PCM  = (float*)(ws + alloc((size_t)64 * 1280 * 4));
  float* CPR  = (float*)(ws + alloc(1280 * 4));

  const int BIG = 1 << 30;

  // --- graph normalization + weight prep ---
  rowsum_dis<<<4096, 256, 0, stream>>>(A, DIS);
  wrow_kernel<<<4096, 256, 0, stream>>>(A, DIS, IWROW);
  wcol_part<<<dim3(16, 32), 256, 0, stream>>>(A, DIS, WCP);
  wcol_fin<<<16, 256, 0, stream>>>(WCP, DIS, IWCOL);
  prep_weights<<<2512, 256, 0, stream>>>(lin_out, conv1w, conv2w, Wpsi, embt,
                                         CW1T, CW2T, WPST, LWOB, QS);
  wq_prep<<<129, 256, 0, stream>>>(lin_in, bpsi, WPST, WQ, BQ);
  build_P<<<dim3(64, 64), 256, 0, stream>>>(A, DIS, IWROW, IWCOL, PCAT, PV, PVT);

  // M2 = Pv@Pv into Pcat cols [4096,8192): storeT (coalesced epilogue)
  gemm256<1, 0><<<256, 512, 0, stream>>>(PVT, 4096, PV, 4096, PCAT + 4096, 8192, 4096);

  for (int l = 0; l < 2; ++l) {
    convert_X<<<16384, 256, 0, stream>>>(embs + (long)l * 32 * 4000 * 128, XBF);
    // BT1[s*128+e, w*4096+n] = (X_s @ W1w)[n,e]
    gemm_smallk<0, 128, 2, 0><<<dim3(32, 2, 32), 256, 0, stream>>>(
        XBF, XBF, BIG, 128, 4096, CW1T, 128,
        BT, 8192L, 1L, 128L * 8192, 4096L, nullptr, nullptr, nullptr, nullptr);
    // H1 = relu(Pcat @ BT1)
    gemm256<0, 1><<<256, 512, 0, stream>>>(PCAT, 8192, BT, 8192, HBUF, 4096, 8192);
    // BT2 from H1
    gemm_smallk<0, 128, 2, 0><<<dim3(32, 2, 32), 256, 0, stream>>>(
        HBUF, HBUF, BIG, 128, 4096, CW2T, 128,
        BT, 8192L, 1L, 128L * 8192, 4096L, nullptr, nullptr, nullptr, nullptr);
    // H2 = Pcat @ BT2 (no relu)
    gemm256<0, 0><<<256, 512, 0, stream>>>(PCAT, 8192, BT, 8192, HBUF, 4096, 8192);
    // fused = [0.5*H2 | 0.5*X] @ Wpsi + b -> Ff  AND  (z==32) q -> QBUF
    gemm_smallk<2, 256, 1, 1><<<dim3(32, 1, 33), 256, 0, stream>>>(
        HBUF, XBF, 128, 128, 4096, WPST, 256,
        Ff, 1L, 4096L, 128L, 0L, bpsi, WQ, QBUF, BQ);
    // attention core -> CAT rows for this layer
    attention2<<<4096, 128, 0, stream>>>(Ff, QBUF, ae, ab, CAT + (size_t)l * 4096 * 256);
  }

  // OUTS = tanh(CAT @ lin_out^T) + TT = tanh(OUTS), scatter to [2][4000][128]
  gemm_smallk<3, 256, 1, 0><<<dim3(64, 1, 1), 256, 0, stream>>>(
      CAT, CAT, BIG, 0, 256, LWOB, 256,
      OUTS, 0L, 0L, 0L, 0L, nullptr, nullptr, TT, nullptr);

  betas_part<<<dim3(64, 2, 8), 256, 0, stream>>>(QS, TT, BRAWP);
  bnorm_kernel<<<64, 256, 0, stream>>>(BRAWP, BNRM);
  z_kernel<<<2000, 256, 0, stream>>>(OUTS, BNRM, ZB);
  p_kernel<<<1000, 256, 0, stream>>>(ZB, Wp, PP);
  ap_kernel<<<4000, 256, 0, stream>>>(A, PP, APB);
  etacm_part<<<64, 256, 0, stream>>>(PP, APB, ZB, PETA, PCM);
  final_small<<<1, 256, 0, stream>>>(PETA, PCM, Wc, CPR);
  out_kernel<<<2000, 256, 0, stream>>>(PP, CPR, out);
}